// Round 6
// baseline (1465.571 us; speedup 1.0000x reference)
//
#include <hip/hip_runtime.h>

#define GAS __attribute__((address_space(1)))
#define LAS __attribute__((address_space(3)))

typedef __attribute__((ext_vector_type(8))) short bf16x8;
typedef __attribute__((ext_vector_type(4))) float f32x4;
typedef __attribute__((ext_vector_type(2))) float f32x2;

static constexpr int Bb = 16, Ll = 2048, Hh = 512, Vv = 32000, H2 = 1024;
static constexpr int Mtot = Bb * Ll;  // 32768
static constexpr float LRc = 0.01f, EPSc = 1e-5f;

// ---- ws layout (bytes) ----
static constexpr size_t OFF_X    = 0;                                   // Mtot*Hh*4
static constexpr size_t OFF_EBF  = OFF_X   + (size_t)Mtot * Hh * 4;     // Vv*Hh*2
static constexpr size_t OFF_W1BF = OFF_EBF + (size_t)Vv * Hh * 2;       // H2*Hh*2
static constexpr size_t OFF_W2BF = OFF_W1BF + (size_t)H2 * Hh * 2;      // Hh*H2*2
static constexpr size_t OFF_CTX  = OFF_W2BF + (size_t)Hh * H2 * 2;      // Bb*Hh*4
static constexpr size_t OFF_FF1  = OFF_CTX + (size_t)Bb * Hh * 4;       // chunk of ff1 (bf16)

__device__ inline unsigned short f2bf(float f) {  // RNE f32 -> bf16
  unsigned u = __float_as_uint(f);
  return (unsigned short)((u + 0x7fffu + ((u >> 16) & 1u)) >> 16);
}

__device__ inline f32x2 pk_fma(f32x2 a, f32x2 b, f32x2 c) { return a * b + c; }

// ---------------- f32 -> bf16 conversion ----------------
__global__ __launch_bounds__(256) void cvt_bf16_kernel(const float* __restrict__ src,
                                                       unsigned short* __restrict__ dst, int n8) {
  int stride = gridDim.x * blockDim.x;
  for (int i = blockIdx.x * blockDim.x + threadIdx.x; i < n8; i += stride) {
    const float4* p = (const float4*)(src + (size_t)i * 8);
    float4 a = p[0], b = p[1];
    uint4 o;
    o.x = f2bf(a.x) | ((unsigned)f2bf(a.y) << 16);
    o.y = f2bf(a.z) | ((unsigned)f2bf(a.w) << 16);
    o.z = f2bf(b.x) | ((unsigned)f2bf(b.y) << 16);
    o.w = f2bf(b.z) | ((unsigned)f2bf(b.w) << 16);
    *(uint4*)(dst + (size_t)i * 8) = o;
  }
}

// ---------------- bf16 GEMM, B^T layout, 128x128 tile, BK=32 (m97 structure) ----------------
template <int KTOT, bool GATHER, bool RELUOUT>
__global__ __launch_bounds__(256) void gemm_bt(const unsigned short* __restrict__ Abase,
                                               const int* __restrict__ seq, int seq_off,
                                               const unsigned short* __restrict__ Bmat,
                                               const float* __restrict__ bias,
                                               unsigned short* __restrict__ outb,
                                               float* __restrict__ outf,
                                               int out_row_off, int ldout) {
  __shared__ unsigned short As[128 * 32];
  __shared__ unsigned short Bs[128 * 32];
  __shared__ unsigned long long aoff[128];
  const int tid = threadIdx.x;
  const int m0 = blockIdx.x * 128, n0 = blockIdx.y * 128;

  if (tid < 128) {
    long long r;
    if (GATHER) r = (long long)seq[seq_off + m0 + tid] * KTOT;
    else        r = (long long)(m0 + tid) * KTOT;
    aoff[tid] = (unsigned long long)r;
  }
  __syncthreads();

  const int srow = tid >> 2;
  const int scol = (tid & 3) * 8;
  const int wave = tid >> 6;
  const int lane = tid & 63;
  const int wr = wave >> 1, wc = wave & 1;
  const int fr = lane & 15;
  const int fk = (lane >> 4) * 8;

  f32x4 acc[4][4] = {};

  for (int k0 = 0; k0 < KTOT; k0 += 32) {
#pragma unroll
    for (int i = 0; i < 2; ++i) {
      const unsigned short* ga = Abase + aoff[i * 64 + srow] + k0 + scol;
      __builtin_amdgcn_global_load_lds((const GAS void*)ga,
          (LAS void*)((char*)As + i * 4096 + wave * 1024), 16, 0, 0);
      const unsigned short* gb = Bmat + (size_t)(n0 + i * 64 + srow) * KTOT + k0 + scol;
      __builtin_amdgcn_global_load_lds((const GAS void*)gb,
          (LAS void*)((char*)Bs + i * 4096 + wave * 1024), 16, 0, 0);
    }
    __syncthreads();
    bf16x8 af[4], bfr[4];
#pragma unroll
    for (int m = 0; m < 4; ++m)
      af[m] = *(const bf16x8*)&As[(wr * 64 + m * 16 + fr) * 32 + fk];
#pragma unroll
    for (int n = 0; n < 4; ++n)
      bfr[n] = *(const bf16x8*)&Bs[(wc * 64 + n * 16 + fr) * 32 + fk];
#pragma unroll
    for (int m = 0; m < 4; ++m)
#pragma unroll
      for (int n = 0; n < 4; ++n)
        acc[m][n] = __builtin_amdgcn_mfma_f32_16x16x32_bf16(af[m], bfr[n], acc[m][n], 0, 0, 0);
    __syncthreads();
  }

  float bv[4];
#pragma unroll
  for (int n = 0; n < 4; ++n) bv[n] = bias[n0 + wc * 64 + n * 16 + fr];
#pragma unroll
  for (int m = 0; m < 4; ++m) {
#pragma unroll
    for (int n = 0; n < 4; ++n) {
#pragma unroll
      for (int j = 0; j < 4; ++j) {
        int rl = wr * 64 + m * 16 + ((lane >> 4) << 2) + j;
        int col = n0 + wc * 64 + n * 16 + fr;
        float v = acc[m][n][j] + bv[n];
        size_t off = (size_t)(out_row_off + m0 + rl) * ldout + col;
        if (RELUOUT) { v = fmaxf(v, 0.f); outb[off] = f2bf(v); }
        else outf[off] = v;
      }
    }
  }
}

// ---------------- residual add + LayerNorm ----------------
__global__ __launch_bounds__(256) void ln_kernel(float* __restrict__ xbuf,
                                                 const float* __restrict__ embed,
                                                 const int* __restrict__ seq,
                                                 const float* __restrict__ lnw,
                                                 const float* __restrict__ lnb) {
  int row = blockIdx.x * 4 + (threadIdx.x >> 6);
  int lane = threadIdx.x & 63;
  int c = lane * 8;
  int s = seq[row];
  float* xr = xbuf + (size_t)row * Hh;
  const float* hr = embed + (size_t)s * Hh;
  float4 f0 = *(const float4*)(xr + c), f1 = *(const float4*)(xr + c + 4);
  float4 h0 = *(const float4*)(hr + c), h1 = *(const float4*)(hr + c + 4);
  float x[8] = {f0.x + h0.x, f0.y + h0.y, f0.z + h0.z, f0.w + h0.w,
                f1.x + h1.x, f1.y + h1.y, f1.z + h1.z, f1.w + h1.w};
  float sm = 0.f, sq = 0.f;
#pragma unroll
  for (int u = 0; u < 8; ++u) { sm += x[u]; sq += x[u] * x[u]; }
#pragma unroll
  for (int m = 1; m < 64; m <<= 1) { sm += __shfl_xor(sm, m, 64); sq += __shfl_xor(sq, m, 64); }
  float mu = sm * (1.f / 512.f);
  float var = sq * (1.f / 512.f) - mu * mu;
  float rs = rsqrtf(var + EPSc);
  float y[8];
#pragma unroll
  for (int u = 0; u < 8; ++u) y[u] = (x[u] - mu) * rs * lnw[c + u] + lnb[c + u];
  *(float4*)(xr + c) = make_float4(y[0], y[1], y[2], y[3]);
  *(float4*)(xr + c + 4) = make_float4(y[4], y[5], y[6], y[7]);
}

// ---------------- TTT scan v6: single wave, one 17-chain interleaved butterfly ----------------
// Lane l owns cols 8l..8l+7 (k, W1) and rows 8l..8l+7 (v, W2, pred).
// Shadow identity (validated R2/R3): z_t = S + b1_{t-1} + dzL_{t-1}*(kappa+1),
//   S = W1_{t-1} k_t, kappa = k_{t-1}.k_t, dzL = -LR*dz.
// All 17 reduce chains (8 dhL, 8 S, 1 kappa) batched into ONE 6-stage shfl_xor
// butterfly, stages textually interleaved 17-wide -> in-order issue hides latency.
// Totals are uniform VGPRs in all lanes (no readlane, no LDS, no barrier).
__global__ __launch_bounds__(64, 1) void ttt_kernel(const float* __restrict__ hidden,
                                                    const float* __restrict__ w1_0,
                                                    const float* __restrict__ b1_0,
                                                    const float* __restrict__ w2_0,
                                                    const float* __restrict__ b2_0,
                                                    float* __restrict__ ctx) {
  const int b = blockIdx.x;
  const int l = threadIdx.x;
  const int c0 = l * 8;
  const float* hb = hidden + (size_t)b * Ll * Hh;
  const float cs = -LRc * 2.0f / 512.0f;  // d-scale with LR folded (dL = -LR*d)

  f32x2 W1v[8][4];  // W1v[j][p] = W1[j][c0+2p .. c0+2p+1]
  f32x2 W2v[8][4];  // W2v[u][p] = W2[c0+u][2p .. 2p+1]
  float B1u[8];     // uniform
  float B2[8];      // per-lane
#pragma unroll
  for (int j = 0; j < 8; ++j) {
    float4 a = *(const float4*)(w1_0 + (size_t)j * Hh + c0);
    float4 d = *(const float4*)(w1_0 + (size_t)j * Hh + c0 + 4);
    W1v[j][0] = f32x2{a.x, a.y}; W1v[j][1] = f32x2{a.z, a.w};
    W1v[j][2] = f32x2{d.x, d.y}; W1v[j][3] = f32x2{d.z, d.w};
    B1u[j] = b1_0[j];
  }
#pragma unroll
  for (int u = 0; u < 8; ++u) {
    float4 a = *(const float4*)(w2_0 + (size_t)(c0 + u) * 8);
    float4 d = *(const float4*)(w2_0 + (size_t)(c0 + u) * 8 + 4);
    W2v[u][0] = f32x2{a.x, a.y}; W2v[u][1] = f32x2{a.z, a.w};
    W2v[u][2] = f32x2{d.x, d.y}; W2v[u][3] = f32x2{d.z, d.w};
  }
  {
    float4 e = *(const float4*)(b2_0 + c0);
    float4 f = *(const float4*)(b2_0 + c0 + 4);
    B2[0] = e.x; B2[1] = e.y; B2[2] = e.z; B2[3] = e.w;
    B2[4] = f.x; B2[5] = f.y; B2[6] = f.z; B2[7] = f.w;
  }

  // k_t = row 2t, v_t = row 2t+1.
  f32x2 Kp[4], Kc[4], Kn[4];
  float Vs[8];
  {
    const float* p0 = hb + c0;  // k_0
    float4 a = *(const float4*)p0, d = *(const float4*)(p0 + 4);
    Kc[0] = f32x2{a.x, a.y}; Kc[1] = f32x2{a.z, a.w};
    Kc[2] = f32x2{d.x, d.y}; Kc[3] = f32x2{d.z, d.w};
    const float* p1 = hb + 2 * Hh + c0;  // k_1
    float4 e = *(const float4*)p1, f = *(const float4*)(p1 + 4);
    Kn[0] = f32x2{e.x, e.y}; Kn[1] = f32x2{e.z, e.w};
    Kn[2] = f32x2{f.x, f.y}; Kn[3] = f32x2{f.z, f.w};
#pragma unroll
    for (int p = 0; p < 4; ++p) Kp[p] = Kc[p];  // dummy (dzL_{-1}=0)
    const float* pv = hb + Hh + c0;  // v_0
    float4 g = *(const float4*)pv, h4 = *(const float4*)(pv + 4);
    Vs[0] = g.x; Vs[1] = g.y; Vs[2] = g.z; Vs[3] = g.w;
    Vs[4] = h4.x; Vs[5] = h4.y; Vs[6] = h4.z; Vs[7] = h4.w;
  }

  // pipelined totals entering iter t: ST=W1_{t-1}k_t, dhLT, kapT, zu=z_{t-1}
  float ST[8], dhLT[8], kapT, zu[8];
  {
    f32x2 acc[8] = {};
#pragma unroll
    for (int p = 0; p < 4; ++p)
#pragma unroll
      for (int j = 0; j < 8; ++j) acc[j] = pk_fma(W1v[j][p], Kc[p], acc[j]);
    float ch[8];
#pragma unroll
    for (int j = 0; j < 8; ++j) ch[j] = acc[j].x + acc[j].y;
#pragma unroll
    for (int st = 0; st < 6; ++st) {
      float tmp[8];
#pragma unroll
      for (int c = 0; c < 8; ++c) tmp[c] = __shfl_xor(ch[c], 1 << st, 64);
#pragma unroll
      for (int c = 0; c < 8; ++c) ch[c] += tmp[c];
    }
#pragma unroll
    for (int j = 0; j < 8; ++j) { ST[j] = ch[j]; dhLT[j] = 0.f; zu[j] = -1.f; }
    kapT = 0.f;  // dzL=0 anyway (zu<0)
  }

#pragma unroll 2
  for (int t = 0; t < 1023; ++t) {
    // prefetch k_{t+2} (row 2t+4; t=1022 reads stay inside ws, unused), v_{t+1}
    const float* kr = hb + (size_t)(2 * t + 4) * Hh + c0;
    float4 ka = *(const float4*)kr, kb4 = *(const float4*)(kr + 4);
    const float* vr = hb + (size_t)(2 * t + 3) * Hh + c0;
    float4 va = *(const float4*)vr, vb = *(const float4*)(vr + 4);

    // ---- fixup: dzL_{t-1}, z_t, b1_t, W1_t ----
    float dzL[8], z[8];
    float kap1 = kapT + 1.f;
#pragma unroll
    for (int j = 0; j < 8; ++j) dzL[j] = (zu[j] > 0.f) ? dhLT[j] : 0.f;
#pragma unroll
    for (int j = 0; j < 8; ++j) z[j] = fmaf(dzL[j], kap1, ST[j] + B1u[j]);
#pragma unroll
    for (int j = 0; j < 8; ++j) B1u[j] += dzL[j];
#pragma unroll
    for (int p = 0; p < 4; ++p)
#pragma unroll
      for (int j = 0; j < 8; ++j)
        W1v[j][p] = pk_fma(f32x2{dzL[j], dzL[j]}, Kp[p], W1v[j][p]);

    // ---- forward: h, pred, dL (p-outer: 8-wide independent) ----
    float h[8];
#pragma unroll
    for (int j = 0; j < 8; ++j) h[j] = fmaxf(z[j], 0.f);
    f32x2 h2[4];
#pragma unroll
    for (int p = 0; p < 4; ++p) h2[p] = f32x2{h[2 * p], h[2 * p + 1]};

    f32x2 pac[8] = {};
#pragma unroll
    for (int p = 0; p < 4; ++p)
#pragma unroll
      for (int u = 0; u < 8; ++u) pac[u] = pk_fma(W2v[u][p], h2[p], pac[u]);
    float dL[8];
    f32x2 dd[8];
#pragma unroll
    for (int u = 0; u < 8; ++u) {
      float pred = pac[u].x + pac[u].y + B2[u];
      dL[u] = (pred - Vs[u]) * cs;
      dd[u] = f32x2{dL[u], dL[u]};
    }

    // ---- chains: dhL partials (old W2), S = W1_t.k_{t+1}, kappa ----
    f32x2 dhp[4] = {{0.f, 0.f}, {0.f, 0.f}, {0.f, 0.f}, {0.f, 0.f}};
#pragma unroll
    for (int u = 0; u < 8; ++u)
#pragma unroll
      for (int p = 0; p < 4; ++p) dhp[p] = pk_fma(W2v[u][p], dd[u], dhp[p]);

    f32x2 sac[8] = {};
#pragma unroll
    for (int p = 0; p < 4; ++p)
#pragma unroll
      for (int j = 0; j < 8; ++j) sac[j] = pk_fma(W1v[j][p], Kn[p], sac[j]);
    f32x2 kac = {0.f, 0.f};
#pragma unroll
    for (int p = 0; p < 4; ++p) kac = pk_fma(Kc[p], Kn[p], kac);

    float ch[17];
#pragma unroll
    for (int p = 0; p < 4; ++p) { ch[2 * p] = dhp[p].x; ch[2 * p + 1] = dhp[p].y; }
#pragma unroll
    for (int j = 0; j < 8; ++j) ch[8 + j] = sac[j].x + sac[j].y;
    ch[16] = kac.x + kac.y;

    // ---- ONE batched butterfly, 17-wide interleaved per stage ----
#pragma unroll
    for (int st = 0; st < 6; ++st) {
      float tmp[17];
#pragma unroll
      for (int c = 0; c < 17; ++c) tmp[c] = __shfl_xor(ch[c], 1 << st, 64);
#pragma unroll
      for (int c = 0; c < 17; ++c) ch[c] += tmp[c];
    }

    // ---- W2_{t+1}, b2 (off recurrence path) ----
#pragma unroll
    for (int p = 0; p < 4; ++p)
#pragma unroll
      for (int u = 0; u < 8; ++u) W2v[u][p] = pk_fma(dd[u], h2[p], W2v[u][p]);
#pragma unroll
    for (int u = 0; u < 8; ++u) B2[u] += dL[u];

    // ---- carry & rotate ----
#pragma unroll
    for (int j = 0; j < 8; ++j) { dhLT[j] = ch[j]; ST[j] = ch[8 + j]; zu[j] = z[j]; }
    kapT = ch[16];
#pragma unroll
    for (int p = 0; p < 4; ++p) { Kp[p] = Kc[p]; Kc[p] = Kn[p]; }
    Kn[0] = f32x2{ka.x, ka.y}; Kn[1] = f32x2{ka.z, ka.w};
    Kn[2] = f32x2{kb4.x, kb4.y}; Kn[3] = f32x2{kb4.z, kb4.w};
    Vs[0] = va.x; Vs[1] = va.y; Vs[2] = va.z; Vs[3] = va.w;
    Vs[4] = vb.x; Vs[5] = vb.y; Vs[6] = vb.z; Vs[7] = vb.w;
  }

  // ---- epilogue: finalize step 1022 (W1_f, b1_f), then query ----
  {
    float dzL[8];
#pragma unroll
    for (int j = 0; j < 8; ++j) dzL[j] = (zu[j] > 0.f) ? dhLT[j] : 0.f;
#pragma unroll
    for (int j = 0; j < 8; ++j) B1u[j] += dzL[j];
#pragma unroll
    for (int p = 0; p < 4; ++p)
#pragma unroll
      for (int j = 0; j < 8; ++j)
        W1v[j][p] = pk_fma(f32x2{dzL[j], dzL[j]}, Kp[p], W1v[j][p]);

    const float* pq = hb + (size_t)(Ll - 1) * Hh + c0;
    float4 a = *(const float4*)pq, d = *(const float4*)(pq + 4);
    f32x2 Q[4] = {f32x2{a.x, a.y}, f32x2{a.z, a.w}, f32x2{d.x, d.y}, f32x2{d.z, d.w}};
    f32x2 qac[8] = {};
#pragma unroll
    for (int p = 0; p < 4; ++p)
#pragma unroll
      for (int j = 0; j < 8; ++j) qac[j] = pk_fma(W1v[j][p], Q[p], qac[j]);
    float ch[8];
#pragma unroll
    for (int j = 0; j < 8; ++j) ch[j] = qac[j].x + qac[j].y;
#pragma unroll
    for (int st = 0; st < 6; ++st) {
      float tmp[8];
#pragma unroll
      for (int c = 0; c < 8; ++c) tmp[c] = __shfl_xor(ch[c], 1 << st, 64);
#pragma unroll
      for (int c = 0; c < 8; ++c) ch[c] += tmp[c];
    }
    float hq[8];
#pragma unroll
    for (int j = 0; j < 8; ++j) hq[j] = fmaxf(ch[j] + B1u[j], 0.f);
    f32x2 hq2[4];
#pragma unroll
    for (int p = 0; p < 4; ++p) hq2[p] = f32x2{hq[2 * p], hq[2 * p + 1]};
    f32x2 oac[8] = {};
#pragma unroll
    for (int p = 0; p < 4; ++p)
#pragma unroll
      for (int u = 0; u < 8; ++u) oac[u] = pk_fma(W2v[u][p], hq2[p], oac[u]);
    float o[8];
#pragma unroll
    for (int u = 0; u < 8; ++u) o[u] = oac[u].x + oac[u].y + B2[u];
    float* cp = ctx + (size_t)b * Hh + c0;
    *(float4*)cp = make_float4(o[0], o[1], o[2], o[3]);
    *(float4*)(cp + 4) = make_float4(o[4], o[5], o[6], o[7]);
  }
}

// ---------------- head: out[b,v] = ctx[b,:] @ out_w[v,:] + out_b[v] ----------------
__global__ __launch_bounds__(256) void out_kernel(const float* __restrict__ ctx,
                                                  const float* __restrict__ outw,
                                                  const float* __restrict__ outb_,
                                                  float* __restrict__ out) {
  __shared__ float cs[16 * 516];
  int tid = threadIdx.x;
#pragma unroll
  for (int r = 0; r < 32; ++r) {
    int idx = r * 256 + tid;
    cs[(idx >> 9) * 516 + (idx & 511)] = ctx[idx];
  }
  __syncthreads();
  int v = blockIdx.x * 16 + (tid >> 4);
  int b = tid & 15;
  const float4* wr = (const float4*)(outw + (size_t)v * 512);
  const float4* cr = (const float4*)(cs + b * 516);
  float acc = 0.f;
#pragma unroll 8
  for (int k = 0; k < 128; ++k) {
    float4 wv = wr[k];
    float4 cv = cr[k];
    acc += wv.x * cv.x + wv.y * cv.y + wv.z * cv.z + wv.w * cv.w;
  }
  out[(size_t)b * 32000 + v] = acc + outb_[v];
}

extern "C" void kernel_launch(void* const* d_in, const int* in_sizes, int n_in,
                              void* d_out, int out_size, void* d_ws, size_t ws_size,
                              hipStream_t stream) {
  const int*   seq    = (const int*)d_in[0];
  const float* embed  = (const float*)d_in[1];
  const float* enc_w1 = (const float*)d_in[2];
  const float* enc_b1 = (const float*)d_in[3];
  const float* enc_w2 = (const float*)d_in[4];
  const float* enc_b2 = (const float*)d_in[5];
  const float* ln_w   = (const float*)d_in[6];
  const float* ln_b   = (const float*)d_in[7];
  const float* mlp_w1 = (const float*)d_in[8];
  const float* mlp_b1 = (const float*)d_in[9];
  const float* mlp_w2 = (const float*)d_in[10];
  const float* mlp_b2 = (const float*)d_in[11];
  const float* out_w  = (const float*)d_in[12];
  const float* out_b  = (const float*)d_in[13];
  float* out = (float*)d_out;

  char* ws = (char*)d_ws;
  float*          xbuf = (float*)(ws + OFF_X);
  unsigned short* ebf  = (unsigned short*)(ws + OFF_EBF);
  unsigned short* w1bf = (unsigned short*)(ws + OFF_W1BF);
  unsigned short* w2bf = (unsigned short*)(ws + OFF_W2BF);
  float*          ctx  = (float*)(ws + OFF_CTX);
  unsigned short* ff1  = (unsigned short*)(ws + OFF_FF1);

  const int cand[4] = {1, 2, 4, 8};
  int nc = 8;
  for (int ci = 0; ci < 4; ++ci) {
    if (OFF_FF1 + (size_t)(Mtot / cand[ci]) * H2 * 2 <= ws_size) { nc = cand[ci]; break; }
  }

  cvt_bf16_kernel<<<2048, 256, 0, stream>>>(embed, ebf, Vv * Hh / 8);
  cvt_bf16_kernel<<<256, 256, 0, stream>>>(enc_w1, w1bf, H2 * Hh / 8);
  cvt_bf16_kernel<<<256, 256, 0, stream>>>(enc_w2, w2bf, Hh * H2 / 8);

  const int Mc = Mtot / nc;
  for (int c = 0; c < nc; ++c) {
    const int m0 = c * Mc;
    gemm_bt<512, true, true><<<dim3(Mc / 128, 8), 256, 0, stream>>>(
        ebf, seq, m0, w1bf, enc_b1, ff1, nullptr, 0, H2);
    gemm_bt<1024, false, false><<<dim3(Mc / 128, 4), 256, 0, stream>>>(
        ff1, nullptr, 0, w2bf, enc_b2, nullptr, xbuf, m0, Hh);
  }
  ln_kernel<<<Mtot / 4, 256, 0, stream>>>(xbuf, embed, seq, ln_w, ln_b);
  ttt_kernel<<<Bb, 64, 0, stream>>>(xbuf, mlp_w1, mlp_b1, mlp_w2, mlp_b2, ctx);
  out_kernel<<<Vv / 16, 256, 0, stream>>>(ctx, out_w, out_b, out);
}

// Round 7
// 1033.244 us; speedup vs baseline: 1.4184x; 1.4184x over previous
//
#include <hip/hip_runtime.h>

#define GAS __attribute__((address_space(1)))
#define LAS __attribute__((address_space(3)))

typedef __attribute__((ext_vector_type(8))) short bf16x8;
typedef __attribute__((ext_vector_type(4))) float f32x4;
typedef __attribute__((ext_vector_type(2))) float f32x2;

static constexpr int Bb = 16, Ll = 2048, Hh = 512, Vv = 32000, H2 = 1024;
static constexpr int Mtot = Bb * Ll;  // 32768
static constexpr float LRc = 0.01f, EPSc = 1e-5f;

// ---- ws layout (bytes) ----
static constexpr size_t OFF_X    = 0;                                   // Mtot*Hh*4
static constexpr size_t OFF_EBF  = OFF_X   + (size_t)Mtot * Hh * 4;     // Vv*Hh*2
static constexpr size_t OFF_W1BF = OFF_EBF + (size_t)Vv * Hh * 2;       // H2*Hh*2
static constexpr size_t OFF_W2BF = OFF_W1BF + (size_t)H2 * Hh * 2;      // Hh*H2*2
static constexpr size_t OFF_CTX  = OFF_W2BF + (size_t)Hh * H2 * 2;      // Bb*Hh*4
static constexpr size_t OFF_FF1  = OFF_CTX + (size_t)Bb * Hh * 4;       // chunk of ff1 (bf16)

__device__ inline unsigned short f2bf(float f) {  // RNE f32 -> bf16
  unsigned u = __float_as_uint(f);
  return (unsigned short)((u + 0x7fffu + ((u >> 16) & 1u)) >> 16);
}

__device__ inline f32x2 pk_fma(f32x2 a, f32x2 b, f32x2 c) { return a * b + c; }

// ---- all-lane 64-wide sum butterfly, pure VALU ----
// xor1/2: quad_perm; xor4: row_half_mirror; xor8: row_mirror (valid because
// each 2^s group is uniform after stage s, and mirrors map groups onto each
// other). xor16/32: gfx950 v_permlane{16,32}_swap_b32 (VALU cross-lane): with
// both operands = x, the two results sum to x[l] + x[l^16/32] in EVERY lane.
__device__ __forceinline__ float fold16(float x) {
#if __has_builtin(__builtin_amdgcn_permlane16_swap)
  auto r = __builtin_amdgcn_permlane16_swap(__float_as_uint(x), __float_as_uint(x), false, false);
  return __uint_as_float(r[0]) + __uint_as_float(r[1]);
#else
  return x + __int_as_float(__builtin_amdgcn_ds_swizzle(__float_as_int(x), 0x401F));  // xor16
#endif
}
__device__ __forceinline__ float fold32(float x) {
#if __has_builtin(__builtin_amdgcn_permlane32_swap)
  auto r = __builtin_amdgcn_permlane32_swap(__float_as_uint(x), __float_as_uint(x), false, false);
  return __uint_as_float(r[0]) + __uint_as_float(r[1]);
#else
  return x + __shfl_xor(x, 32, 64);
#endif
}

#define BFLY_STAGE(N, ch, CTRL)                                              \
  _Pragma("unroll") for (int c_ = 0; c_ < (N); ++c_) {                       \
    int t_ = __builtin_amdgcn_update_dpp(0, __float_as_int(ch[c_]), (CTRL),  \
                                         0xf, 0xf, true);                    \
    ch[c_] += __int_as_float(t_);                                            \
  }

template <int N>
__device__ __forceinline__ void bfly64(float (&ch)[N]) {
  BFLY_STAGE(N, ch, 0xB1)   // quad_perm [1,0,3,2]  xor1
  BFLY_STAGE(N, ch, 0x4E)   // quad_perm [2,3,0,1]  xor2
  BFLY_STAGE(N, ch, 0x141)  // row_half_mirror      xor4
  BFLY_STAGE(N, ch, 0x140)  // row_mirror           xor8
#pragma unroll
  for (int c = 0; c < N; ++c) ch[c] = fold16(ch[c]);
#pragma unroll
  for (int c = 0; c < N; ++c) ch[c] = fold32(ch[c]);
}

// ---------------- f32 -> bf16 conversion ----------------
__global__ __launch_bounds__(256) void cvt_bf16_kernel(const float* __restrict__ src,
                                                       unsigned short* __restrict__ dst, int n8) {
  int stride = gridDim.x * blockDim.x;
  for (int i = blockIdx.x * blockDim.x + threadIdx.x; i < n8; i += stride) {
    const float4* p = (const float4*)(src + (size_t)i * 8);
    float4 a = p[0], b = p[1];
    uint4 o;
    o.x = f2bf(a.x) | ((unsigned)f2bf(a.y) << 16);
    o.y = f2bf(a.z) | ((unsigned)f2bf(a.w) << 16);
    o.z = f2bf(b.x) | ((unsigned)f2bf(b.y) << 16);
    o.w = f2bf(b.z) | ((unsigned)f2bf(b.w) << 16);
    *(uint4*)(dst + (size_t)i * 8) = o;
  }
}

// ---------------- bf16 GEMM, B^T layout, 128x128 tile, BK=32 (m97 structure) ----------------
template <int KTOT, bool GATHER, bool RELUOUT>
__global__ __launch_bounds__(256) void gemm_bt(const unsigned short* __restrict__ Abase,
                                               const int* __restrict__ seq, int seq_off,
                                               const unsigned short* __restrict__ Bmat,
                                               const float* __restrict__ bias,
                                               unsigned short* __restrict__ outb,
                                               float* __restrict__ outf,
                                               int out_row_off, int ldout) {
  __shared__ unsigned short As[128 * 32];
  __shared__ unsigned short Bs[128 * 32];
  __shared__ unsigned long long aoff[128];
  const int tid = threadIdx.x;
  const int m0 = blockIdx.x * 128, n0 = blockIdx.y * 128;

  if (tid < 128) {
    long long r;
    if (GATHER) r = (long long)seq[seq_off + m0 + tid] * KTOT;
    else        r = (long long)(m0 + tid) * KTOT;
    aoff[tid] = (unsigned long long)r;
  }
  __syncthreads();

  const int srow = tid >> 2;
  const int scol = (tid & 3) * 8;
  const int wave = tid >> 6;
  const int lane = tid & 63;
  const int wr = wave >> 1, wc = wave & 1;
  const int fr = lane & 15;
  const int fk = (lane >> 4) * 8;

  f32x4 acc[4][4] = {};

  for (int k0 = 0; k0 < KTOT; k0 += 32) {
#pragma unroll
    for (int i = 0; i < 2; ++i) {
      const unsigned short* ga = Abase + aoff[i * 64 + srow] + k0 + scol;
      __builtin_amdgcn_global_load_lds((const GAS void*)ga,
          (LAS void*)((char*)As + i * 4096 + wave * 1024), 16, 0, 0);
      const unsigned short* gb = Bmat + (size_t)(n0 + i * 64 + srow) * KTOT + k0 + scol;
      __builtin_amdgcn_global_load_lds((const GAS void*)gb,
          (LAS void*)((char*)Bs + i * 4096 + wave * 1024), 16, 0, 0);
    }
    __syncthreads();
    bf16x8 af[4], bfr[4];
#pragma unroll
    for (int m = 0; m < 4; ++m)
      af[m] = *(const bf16x8*)&As[(wr * 64 + m * 16 + fr) * 32 + fk];
#pragma unroll
    for (int n = 0; n < 4; ++n)
      bfr[n] = *(const bf16x8*)&Bs[(wc * 64 + n * 16 + fr) * 32 + fk];
#pragma unroll
    for (int m = 0; m < 4; ++m)
#pragma unroll
      for (int n = 0; n < 4; ++n)
        acc[m][n] = __builtin_amdgcn_mfma_f32_16x16x32_bf16(af[m], bfr[n], acc[m][n], 0, 0, 0);
    __syncthreads();
  }

  float bv[4];
#pragma unroll
  for (int n = 0; n < 4; ++n) bv[n] = bias[n0 + wc * 64 + n * 16 + fr];
#pragma unroll
  for (int m = 0; m < 4; ++m) {
#pragma unroll
    for (int n = 0; n < 4; ++n) {
#pragma unroll
      for (int j = 0; j < 4; ++j) {
        int rl = wr * 64 + m * 16 + ((lane >> 4) << 2) + j;
        int col = n0 + wc * 64 + n * 16 + fr;
        float v = acc[m][n][j] + bv[n];
        size_t off = (size_t)(out_row_off + m0 + rl) * ldout + col;
        if (RELUOUT) { v = fmaxf(v, 0.f); outb[off] = f2bf(v); }
        else outf[off] = v;
      }
    }
  }
}

// ---------------- residual add + LayerNorm ----------------
__global__ __launch_bounds__(256) void ln_kernel(float* __restrict__ xbuf,
                                                 const float* __restrict__ embed,
                                                 const int* __restrict__ seq,
                                                 const float* __restrict__ lnw,
                                                 const float* __restrict__ lnb) {
  int row = blockIdx.x * 4 + (threadIdx.x >> 6);
  int lane = threadIdx.x & 63;
  int c = lane * 8;
  int s = seq[row];
  float* xr = xbuf + (size_t)row * Hh;
  const float* hr = embed + (size_t)s * Hh;
  float4 f0 = *(const float4*)(xr + c), f1 = *(const float4*)(xr + c + 4);
  float4 h0 = *(const float4*)(hr + c), h1 = *(const float4*)(hr + c + 4);
  float x[8] = {f0.x + h0.x, f0.y + h0.y, f0.z + h0.z, f0.w + h0.w,
                f1.x + h1.x, f1.y + h1.y, f1.z + h1.z, f1.w + h1.w};
  float sm = 0.f, sq = 0.f;
#pragma unroll
  for (int u = 0; u < 8; ++u) { sm += x[u]; sq += x[u] * x[u]; }
#pragma unroll
  for (int m = 1; m < 64; m <<= 1) { sm += __shfl_xor(sm, m, 64); sq += __shfl_xor(sq, m, 64); }
  float mu = sm * (1.f / 512.f);
  float var = sq * (1.f / 512.f) - mu * mu;
  float rs = rsqrtf(var + EPSc);
  float y[8];
#pragma unroll
  for (int u = 0; u < 8; ++u) y[u] = (x[u] - mu) * rs * lnw[c + u] + lnb[c + u];
  *(float4*)(xr + c) = make_float4(y[0], y[1], y[2], y[3]);
  *(float4*)(xr + c + 4) = make_float4(y[4], y[5], y[6], y[7]);
}

// ---------------- TTT scan v7: single wave, direct dataflow, all-VALU butterflies ----------------
// Lane l owns cols 8l..8l+7 (k, W1) and rows 8l..8l+7 (v, W2, pred).
// Per step: z = W1_t k_t + b1 (8-chain bfly) -> h -> pred/dL (lane-local) ->
// dh (8-chain bfly, OLD W2) -> W2 update -> dzL -> W1 update. No LDS, no
// barrier, no readlane; reduces are batched stage-outer so in-order issue
// hides DPP latency. LR and 2/512 folded into dL.
__global__ __launch_bounds__(64, 1) void ttt_kernel(const float* __restrict__ hidden,
                                                    const float* __restrict__ w1_0,
                                                    const float* __restrict__ b1_0,
                                                    const float* __restrict__ w2_0,
                                                    const float* __restrict__ b2_0,
                                                    float* __restrict__ ctx) {
  const int b = blockIdx.x;
  const int l = threadIdx.x;
  const int c0 = l * 8;
  const float* hb = hidden + (size_t)b * Ll * Hh;
  const float cs = -LRc * 2.0f / 512.0f;  // dL = (pred - v) * cs  (-LR folded)

  f32x2 W1v[8][4];  // W1v[j][p] = W1[j][c0+2p .. c0+2p+1]
  f32x2 W2v[8][4];  // W2v[u][p] = W2[c0+u][2p .. 2p+1]
  float B1u[8];     // uniform across lanes
  float B2[8];      // per-lane rows
#pragma unroll
  for (int j = 0; j < 8; ++j) {
    float4 a = *(const float4*)(w1_0 + (size_t)j * Hh + c0);
    float4 d = *(const float4*)(w1_0 + (size_t)j * Hh + c0 + 4);
    W1v[j][0] = f32x2{a.x, a.y}; W1v[j][1] = f32x2{a.z, a.w};
    W1v[j][2] = f32x2{d.x, d.y}; W1v[j][3] = f32x2{d.z, d.w};
    B1u[j] = b1_0[j];
  }
#pragma unroll
  for (int u = 0; u < 8; ++u) {
    float4 a = *(const float4*)(w2_0 + (size_t)(c0 + u) * 8);
    float4 d = *(const float4*)(w2_0 + (size_t)(c0 + u) * 8 + 4);
    W2v[u][0] = f32x2{a.x, a.y}; W2v[u][1] = f32x2{a.z, a.w};
    W2v[u][2] = f32x2{d.x, d.y}; W2v[u][3] = f32x2{d.z, d.w};
  }
  {
    float4 e = *(const float4*)(b2_0 + c0);
    float4 f = *(const float4*)(b2_0 + c0 + 4);
    B2[0] = e.x; B2[1] = e.y; B2[2] = e.z; B2[3] = e.w;
    B2[4] = f.x; B2[5] = f.y; B2[6] = f.z; B2[7] = f.w;
  }

  // k_t = row 2t (cols c0..c0+7), v_t = row 2t+1 (elements c0..c0+7)
  f32x2 Kc[4];
  float Vs[8];
  {
    const float* p0 = hb + c0;
    float4 a = *(const float4*)p0, d = *(const float4*)(p0 + 4);
    Kc[0] = f32x2{a.x, a.y}; Kc[1] = f32x2{a.z, a.w};
    Kc[2] = f32x2{d.x, d.y}; Kc[3] = f32x2{d.z, d.w};
    const float* pv = hb + Hh + c0;
    float4 g = *(const float4*)pv, h4 = *(const float4*)(pv + 4);
    Vs[0] = g.x; Vs[1] = g.y; Vs[2] = g.z; Vs[3] = g.w;
    Vs[4] = h4.x; Vs[5] = h4.y; Vs[6] = h4.z; Vs[7] = h4.w;
  }

#pragma unroll 2
  for (int t = 0; t < 1023; ++t) {
    // prefetch k_{t+1} (row 2t+2), v_{t+1} (row 2t+3); at t=1022 these read
    // rows 2046/2047 (valid memory), values unused.
    const float* kr = hb + (size_t)(2 * t + 2) * Hh + c0;
    float4 ka = *(const float4*)kr, kb4 = *(const float4*)(kr + 4);
    const float* vr = hb + (size_t)(2 * t + 3) * Hh + c0;
    float4 va = *(const float4*)vr, vb = *(const float4*)(vr + 4);

    // ---- z = W1_t k_t + b1 ----
    f32x2 zac[8] = {};
#pragma unroll
    for (int p = 0; p < 4; ++p)
#pragma unroll
      for (int j = 0; j < 8; ++j) zac[j] = pk_fma(W1v[j][p], Kc[p], zac[j]);
    float zch[8];
#pragma unroll
    for (int j = 0; j < 8; ++j) zch[j] = zac[j].x + zac[j].y;
    bfly64<8>(zch);
    float z[8], h[8];
#pragma unroll
    for (int j = 0; j < 8; ++j) { z[j] = zch[j] + B1u[j]; h[j] = fmaxf(z[j], 0.f); }
    f32x2 h2[4];
#pragma unroll
    for (int p = 0; p < 4; ++p) h2[p] = f32x2{h[2 * p], h[2 * p + 1]};

    // ---- pred, dL (lane-local rows) ----
    f32x2 pac[8] = {};
#pragma unroll
    for (int p = 0; p < 4; ++p)
#pragma unroll
      for (int u = 0; u < 8; ++u) pac[u] = pk_fma(W2v[u][p], h2[p], pac[u]);
    float dL[8];
    f32x2 dd[8];
#pragma unroll
    for (int u = 0; u < 8; ++u) {
      float pred = pac[u].x + pac[u].y + B2[u];
      dL[u] = (pred - Vs[u]) * cs;
      dd[u] = f32x2{dL[u], dL[u]};
    }

    // ---- dh partials over OLD W2 (8 accumulators: u split even/odd) ----
    f32x2 dha[4] = {}, dhb[4] = {};
#pragma unroll
    for (int u = 0; u < 8; u += 2)
#pragma unroll
      for (int p = 0; p < 4; ++p) {
        dha[p] = pk_fma(W2v[u][p], dd[u], dha[p]);
        dhb[p] = pk_fma(W2v[u + 1][p], dd[u + 1], dhb[p]);
      }
    float dch[8];
#pragma unroll
    for (int p = 0; p < 4; ++p) {
      f32x2 s = dha[p] + dhb[p];
      dch[2 * p] = s.x; dch[2 * p + 1] = s.y;
    }
    bfly64<8>(dch);

    // ---- W2_{t+1} = W2 + dL h^T ; b2 += dL ----
#pragma unroll
    for (int p = 0; p < 4; ++p)
#pragma unroll
      for (int u = 0; u < 8; ++u) W2v[u][p] = pk_fma(dd[u], h2[p], W2v[u][p]);
#pragma unroll
    for (int u = 0; u < 8; ++u) B2[u] += dL[u];

    // ---- dzL, W1_{t+1} = W1 + dzL k^T ; b1 += dzL ----
    float dzL[8];
#pragma unroll
    for (int j = 0; j < 8; ++j) dzL[j] = (z[j] > 0.f) ? dch[j] : 0.f;
#pragma unroll
    for (int p = 0; p < 4; ++p)
#pragma unroll
      for (int j = 0; j < 8; ++j)
        W1v[j][p] = pk_fma(f32x2{dzL[j], dzL[j]}, Kc[p], W1v[j][p]);
#pragma unroll
    for (int j = 0; j < 8; ++j) B1u[j] += dzL[j];

    // ---- rotate streams ----
    Kc[0] = f32x2{ka.x, ka.y}; Kc[1] = f32x2{ka.z, ka.w};
    Kc[2] = f32x2{kb4.x, kb4.y}; Kc[3] = f32x2{kb4.z, kb4.w};
    Vs[0] = va.x; Vs[1] = va.y; Vs[2] = va.z; Vs[3] = va.w;
    Vs[4] = vb.x; Vs[5] = vb.y; Vs[6] = vb.z; Vs[7] = vb.w;
  }

  // ---- query: row L-1 ----
  {
    const float* pq = hb + (size_t)(Ll - 1) * Hh + c0;
    float4 a = *(const float4*)pq, d = *(const float4*)(pq + 4);
    f32x2 Q[4] = {f32x2{a.x, a.y}, f32x2{a.z, a.w}, f32x2{d.x, d.y}, f32x2{d.z, d.w}};
    f32x2 qac[8] = {};
#pragma unroll
    for (int p = 0; p < 4; ++p)
#pragma unroll
      for (int j = 0; j < 8; ++j) qac[j] = pk_fma(W1v[j][p], Q[p], qac[j]);
    float qch[8];
#pragma unroll
    for (int j = 0; j < 8; ++j) qch[j] = qac[j].x + qac[j].y;
    bfly64<8>(qch);
    float hq[8];
#pragma unroll
    for (int j = 0; j < 8; ++j) hq[j] = fmaxf(qch[j] + B1u[j], 0.f);
    f32x2 hq2[4];
#pragma unroll
    for (int p = 0; p < 4; ++p) hq2[p] = f32x2{hq[2 * p], hq[2 * p + 1]};
    f32x2 oac[8] = {};
#pragma unroll
    for (int p = 0; p < 4; ++p)
#pragma unroll
      for (int u = 0; u < 8; ++u) oac[u] = pk_fma(W2v[u][p], hq2[p], oac[u]);
    float o[8];
#pragma unroll
    for (int u = 0; u < 8; ++u) o[u] = oac[u].x + oac[u].y + B2[u];
    float* cp = ctx + (size_t)b * Hh + c0;
    *(float4*)cp = make_float4(o[0], o[1], o[2], o[3]);
    *(float4*)(cp + 4) = make_float4(o[4], o[5], o[6], o[7]);
  }
}

// ---------------- head: out[b,v] = ctx[b,:] @ out_w[v,:] + out_b[v] ----------------
__global__ __launch_bounds__(256) void out_kernel(const float* __restrict__ ctx,
                                                  const float* __restrict__ outw,
                                                  const float* __restrict__ outb_,
                                                  float* __restrict__ out) {
  __shared__ float cs[16 * 516];
  int tid = threadIdx.x;
#pragma unroll
  for (int r = 0; r < 32; ++r) {
    int idx = r * 256 + tid;
    cs[(idx >> 9) * 516 + (idx & 511)] = ctx[idx];
  }
  __syncthreads();
  int v = blockIdx.x * 16 + (tid >> 4);
  int b = tid & 15;
  const float4* wr = (const float4*)(outw + (size_t)v * 512);
  const float4* cr = (const float4*)(cs + b * 516);
  float acc = 0.f;
#pragma unroll 8
  for (int k = 0; k < 128; ++k) {
    float4 wv = wr[k];
    float4 cv = cr[k];
    acc += wv.x * cv.x + wv.y * cv.y + wv.z * cv.z + wv.w * cv.w;
  }
  out[(size_t)b * 32000 + v] = acc + outb_[v];
}

extern "C" void kernel_launch(void* const* d_in, const int* in_sizes, int n_in,
                              void* d_out, int out_size, void* d_ws, size_t ws_size,
                              hipStream_t stream) {
  const int*   seq    = (const int*)d_in[0];
  const float* embed  = (const float*)d_in[1];
  const float* enc_w1 = (const float*)d_in[2];
  const float* enc_b1 = (const float*)d_in[3];
  const float* enc_w2 = (const float*)d_in[4];
  const float* enc_b2 = (const float*)d_in[5];
  const float* ln_w   = (const float*)d_in[6];
  const float* ln_b   = (const float*)d_in[7];
  const float* mlp_w1 = (const float*)d_in[8];
  const float* mlp_b1 = (const float*)d_in[9];
  const float* mlp_w2 = (const float*)d_in[10];
  const float* mlp_b2 = (const float*)d_in[11];
  const float* out_w  = (const float*)d_in[12];
  const float* out_b  = (const float*)d_in[13];
  float* out = (float*)d_out;

  char* ws = (char*)d_ws;
  float*          xbuf = (float*)(ws + OFF_X);
  unsigned short* ebf  = (unsigned short*)(ws + OFF_EBF);
  unsigned short* w1bf = (unsigned short*)(ws + OFF_W1BF);
  unsigned short* w2bf = (unsigned short*)(ws + OFF_W2BF);
  float*          ctx  = (float*)(ws + OFF_CTX);
  unsigned short* ff1  = (unsigned short*)(ws + OFF_FF1);

  const int cand[4] = {1, 2, 4, 8};
  int nc = 8;
  for (int ci = 0; ci < 4; ++ci) {
    if (OFF_FF1 + (size_t)(Mtot / cand[ci]) * H2 * 2 <= ws_size) { nc = cand[ci]; break; }
  }

  cvt_bf16_kernel<<<2048, 256, 0, stream>>>(embed, ebf, Vv * Hh / 8);
  cvt_bf16_kernel<<<256, 256, 0, stream>>>(enc_w1, w1bf, H2 * Hh / 8);
  cvt_bf16_kernel<<<256, 256, 0, stream>>>(enc_w2, w2bf, Hh * H2 / 8);

  const int Mc = Mtot / nc;
  for (int c = 0; c < nc; ++c) {
    const int m0 = c * Mc;
    gemm_bt<512, true, true><<<dim3(Mc / 128, 8), 256, 0, stream>>>(
        ebf, seq, m0, w1bf, enc_b1, ff1, nullptr, 0, H2);
    gemm_bt<1024, false, false><<<dim3(Mc / 128, 4), 256, 0, stream>>>(
        ff1, nullptr, 0, w2bf, enc_b2, nullptr, xbuf, m0, Hh);
  }
  ln_kernel<<<Mtot / 4, 256, 0, stream>>>(xbuf, embed, seq, ln_w, ln_b);
  ttt_kernel<<<Bb, 64, 0, stream>>>(xbuf, mlp_w1, mlp_b1, mlp_w2, mlp_b2, ctx);
  out_kernel<<<Vv / 16, 256, 0, stream>>>(ctx, out_w, out_b, out);
}